// Round 8
// baseline (205.005 us; speedup 1.0000x reference)
//
#include <hip/hip_runtime.h>
#include <hip/hip_cooperative_groups.h>
#include <hip/hip_bf16.h>

namespace cg = cooperative_groups;

#define BB 4
#define IN_DIM 8
#define OUT_DIM 64
#define N_WIN 64
#define N_SEQ 4096
#define N_REAL 6144

#define ZR 6208   // timeline rows per batch: 63 zero-pad + 6144 + 1 spare

typedef __attribute__((ext_vector_type(8)))  short short8;
typedef __attribute__((ext_vector_type(16))) float floatx16;

static __device__ __forceinline__ unsigned short f2bf(float f) {
    union { float f; unsigned int u; } v; v.f = f;
    unsigned int r = v.u + 0x7fffu + ((v.u >> 16) & 1u);   // round-nearest-even
    return (unsigned short)(r >> 16);
}

// One cooperative kernel:
//   Phase A: gather-build bf16 timeline zf[b][tau+63][i] (every row written
//            exactly once -> no zero pass) + transpose w -> w2[l][o][i]
//   grid.sync()
//   Phase B: MFMA GEMM  out[b,o,t] = sum_{l,i} w[o,i,l] * z[b,i,t-l] + bias[o]
__global__ __launch_bounds__(128)
void k_fused(const float* __restrict__ x, const float* __restrict__ w,
             const float* __restrict__ bias, const int* __restrict__ sidx,
             unsigned short* __restrict__ w2, unsigned short* __restrict__ zf,
             float* __restrict__ out)
{
    __shared__ unsigned short zlds[96 * 8];   // 96 timeline rows x 8 bf16 = 1.5 KB

    const int tid = threadIdx.x;
    const int bx  = blockIdx.x;               // t-tile (0..191)
    const int by  = blockIdx.y;               // batch
    const int g   = (by * 192 + bx) * 128 + tid;

    // ---- Phase A ----
    if (g < BB * ZR) {                        // one thread per timeline row
        const int b   = g / ZR;
        const int q   = g - b * ZR;           // row index within batch
        const int tau = q - 63;
        uint4 pk = make_uint4(0u, 0u, 0u, 0u);
        if ((unsigned)tau < (unsigned)N_REAL) {
            const int* idxb = sidx + b * N_SEQ;         // sorted, unique
            int lo = 0, hi = N_SEQ;
            while (lo < hi) { int m = (lo + hi) >> 1; if (idxb[m] < tau) lo = m + 1; else hi = m; }
            if (lo < N_SEQ && idxb[lo] == tau) {
                const float* xp = x + (size_t)b * IN_DIM * N_SEQ + lo;
                unsigned short v[8];
                #pragma unroll
                for (int i = 0; i < 8; ++i) v[i] = f2bf(xp[(size_t)i * N_SEQ]);
                pk.x = v[0] | ((unsigned)v[1] << 16); pk.y = v[2] | ((unsigned)v[3] << 16);
                pk.z = v[4] | ((unsigned)v[5] << 16); pk.w = v[6] | ((unsigned)v[7] << 16);
            }
        }
        *(uint4*)(zf + (size_t)g * 8) = pk;
    } else if (g < BB * ZR + OUT_DIM * N_WIN) {  // one thread per (o,l): w transpose
        const int tg = g - BB * ZR;
        const int l = tg & 63, o = tg >> 6;
        const float* wp = w + (size_t)o * IN_DIM * N_WIN + l;
        unsigned short v[8];
        #pragma unroll
        for (int i = 0; i < 8; ++i) v[i] = f2bf(wp[(size_t)i * N_WIN]);
        uint4 pk;
        pk.x = v[0] | ((unsigned)v[1] << 16); pk.y = v[2] | ((unsigned)v[3] << 16);
        pk.z = v[4] | ((unsigned)v[5] << 16); pk.w = v[6] | ((unsigned)v[7] << 16);
        *(uint4*)(w2 + ((size_t)l * OUT_DIM + o) * 8) = pk;
    }

    __threadfence();                // device-scope visibility across XCDs
    cg::this_grid().sync();

    // ---- Phase B: block = 32 t x 64 o, 2 waves (one 32-o half each) ----
    const int t0 = bx * 32;
    const int b  = by;

    if (tid < 96)                   // stage rows tau = t0-63 .. t0+32
        *(uint4*)(zlds + tid * 8) =
            *(const uint4*)(zf + ((size_t)b * ZR + t0 + tid) * 8);
    __syncthreads();

    const int mh = tid >> 6;        // wave id: which 32-o half
    const int ln = tid & 31;        // n (t) / m lane coordinate
    const int lq = (tid >> 5) & 1;  // k-half within wave

    floatx16 acc = {};
    const short8* wv = (const short8*)w2;
    const short8* zv = (const short8*)zlds;

    #pragma unroll 8
    for (int ks = 0; ks < 32; ++ks) {
        const int l = 2 * ks + lq;                   // lag for this k-half
        short8 a  = wv[l * OUT_DIM + mh * 32 + ln];  // A[m=o][k=(l,i)]  (L2-hot)
        short8 bz = zv[ln + 63 - l];                 // B[k=(l,i)][n=t]  (LDS b128)
        acc = __builtin_amdgcn_mfma_f32_32x32x16_bf16(a, bz, acc, 0, 0, 0);
    }

    // C/D layout (m74/m101): col=lane&31 -> t, row=(p&3)+8*(p>>2)+4*(lane>>5) -> o
    #pragma unroll
    for (int p = 0; p < 16; ++p) {
        int o = (p & 3) + 8 * (p >> 2) + 4 * lq + mh * 32;
        out[((size_t)b * OUT_DIM + o) * N_REAL + t0 + ln] = acc[p] + bias[o];
    }
}

extern "C" void kernel_launch(void* const* d_in, const int* in_sizes, int n_in,
                              void* d_out, int out_size, void* d_ws, size_t ws_size,
                              hipStream_t stream) {
    const float* px = nullptr; const float* pw = nullptr;
    const float* pb = nullptr; const int* ps = nullptr;

    for (int i = 0; i < n_in; ++i) {
        switch (in_sizes[i]) {
            case BB * IN_DIM * N_SEQ:        px = (const float*)d_in[i]; break; // x
            case OUT_DIM * IN_DIM * N_WIN:   pw = (const float*)d_in[i]; break; // weight
            case OUT_DIM:                    pb = (const float*)d_in[i]; break; // bias
            case BB * N_SEQ:                 ps = (const int*)d_in[i];   break; // sourceIdx
            default: break;
        }
    }
    if (!px || !pw || !pb || !ps) {
        px = (const float*)d_in[0]; pw = (const float*)d_in[1];
        pb = (const float*)d_in[2]; ps = (const int*)d_in[3];
    }

    unsigned short* w2 = (unsigned short*)d_ws;                   // 64 KB
    unsigned short* zf = w2 + N_WIN * OUT_DIM * IN_DIM;           // 388 KB timeline
    float* out = (float*)d_out;

    void* args[] = { (void*)&px, (void*)&pw, (void*)&pb, (void*)&ps,
                     (void*)&w2, (void*)&zf, (void*)&out };
    hipLaunchCooperativeKernel((const void*)k_fused, dim3(192, BB), dim3(128),
                               args, 0, stream);
}

// Round 9
// 72.930 us; speedup vs baseline: 2.8110x; 2.8110x over previous
//
#include <hip/hip_runtime.h>
#include <hip/hip_bf16.h>

#define BB 4
#define IN_DIM 8
#define OUT_DIM 64
#define N_WIN 64
#define N_SEQ 4096
#define N_REAL 6144

typedef __attribute__((ext_vector_type(8)))  short short8;
typedef __attribute__((ext_vector_type(16))) float floatx16;

static __device__ __forceinline__ unsigned short f2bf(float f) {
    union { float f; unsigned int u; } v; v.f = f;
    unsigned int r = v.u + 0x7fffu + ((v.u >> 16) & 1u);   // round-nearest-even
    return (unsigned short)(r >> 16);
}

// ---- K1: transpose/pack weights  w[o][i][l] -> w2[l][o][i] (bf16) ----
__global__ __launch_bounds__(256)
void k_wprep(const float* __restrict__ w, unsigned short* __restrict__ w2)
{
    const int tg = blockIdx.x * 256 + threadIdx.x;   // 0..4095
    const int l = tg >> 6, o = tg & 63;              // consecutive tid -> consecutive o
    const float* wp = w + (size_t)o * (IN_DIM * N_WIN) + l;
    unsigned short v[8];
    #pragma unroll
    for (int i = 0; i < 8; ++i) v[i] = f2bf(wp[(size_t)i * N_WIN]);
    uint4 pk;
    pk.x = v[0] | ((unsigned)v[1] << 16); pk.y = v[2] | ((unsigned)v[3] << 16);
    pk.z = v[4] | ((unsigned)v[5] << 16); pk.w = v[6] | ((unsigned)v[7] << 16);
    *(uint4*)(w2 + ((size_t)(l * OUT_DIM + o)) * 8) = pk;    // coalesced 16B stores
}

// ---- K2: MFMA GEMM with in-block timeline gather (no global timeline) ----
// Block = 32 t x 64 o, 2 waves. out[b,o,t] = sum_{l,i} w[o,i,l]*z[b,i,t-l] + bias[o]
__global__ __launch_bounds__(128)
void k_gemm(const float* __restrict__ x, const unsigned short* __restrict__ w2,
            const float* __restrict__ bias, const int* __restrict__ sidx,
            float* __restrict__ out)
{
    __shared__ unsigned short zlds[96 * 8];   // rows tau = t0-63 .. t0+32 (1.5 KB)

    const int tid = threadIdx.x;
    const int t0  = blockIdx.x * 32;
    const int b   = blockIdx.y;

    // zero the LDS tile (384 dwords)
    unsigned int* zw = (unsigned int*)zlds;
    zw[tid] = 0u; zw[tid + 128] = 0u; zw[tid + 256] = 0u;

    // wave-uniform lower_bound(sidx[b], t0-63)  -> scalar-pipe loads
    const int* idxb = sidx + b * N_SEQ;
    const int vlo = t0 - 63;
    int lo = 0, hi = N_SEQ;
    while (lo < hi) { int m = (lo + hi) >> 1; if (idxb[m] < vlo) lo = m + 1; else hi = m; }

    __syncthreads();   // zeros visible before scatter

    // scatter: window holds <=96 unique sources, contiguous from lo
    if (tid < 96) {
        int s = lo + tid;
        if (s < N_SEQ) {
            int r = idxb[s] - vlo;                 // row in [0,96) if in-window
            if ((unsigned)r < 96u) {
                const float* xp = x + (size_t)b * IN_DIM * N_SEQ + s;
                unsigned short v[8];
                #pragma unroll
                for (int i = 0; i < 8; ++i) v[i] = f2bf(xp[(size_t)i * N_SEQ]);
                uint4 pk;
                pk.x = v[0] | ((unsigned)v[1] << 16); pk.y = v[2] | ((unsigned)v[3] << 16);
                pk.z = v[4] | ((unsigned)v[5] << 16); pk.w = v[6] | ((unsigned)v[7] << 16);
                *(uint4*)(zlds + r * 8) = pk;
            }
        }
    }
    __syncthreads();

    // MFMA main loop (proven R7 structure)
    const int mh = tid >> 6;        // wave id: which 32-o half
    const int ln = tid & 31;        // n (t) / m lane coordinate
    const int lq = (tid >> 5) & 1;  // k-half within wave

    floatx16 acc = {};
    const short8* wv = (const short8*)w2;
    const short8* zv = (const short8*)zlds;

    #pragma unroll 8
    for (int ks = 0; ks < 32; ++ks) {
        const int l = 2 * ks + lq;                   // lag for this k-half
        short8 a  = wv[l * OUT_DIM + mh * 32 + ln];  // A[m=o][k=(l,i)]  (L2/L1-hot)
        short8 bz = zv[ln + 63 - l];                 // B[k=(l,i)][n=t]  (LDS b128)
        acc = __builtin_amdgcn_mfma_f32_32x32x16_bf16(a, bz, acc, 0, 0, 0);
    }

    // C/D layout (m74/m101): col=lane&31 -> t, row=(p&3)+8*(p>>2)+4*(lane>>5) -> o
    #pragma unroll
    for (int p = 0; p < 16; ++p) {
        int o = (p & 3) + 8 * (p >> 2) + 4 * lq + mh * 32;
        out[((size_t)b * OUT_DIM + o) * N_REAL + t0 + ln] = acc[p] + bias[o];
    }
}

extern "C" void kernel_launch(void* const* d_in, const int* in_sizes, int n_in,
                              void* d_out, int out_size, void* d_ws, size_t ws_size,
                              hipStream_t stream) {
    const float* px = nullptr; const float* pw = nullptr;
    const float* pb = nullptr; const int* ps = nullptr;

    for (int i = 0; i < n_in; ++i) {
        switch (in_sizes[i]) {
            case BB * IN_DIM * N_SEQ:        px = (const float*)d_in[i]; break; // x
            case OUT_DIM * IN_DIM * N_WIN:   pw = (const float*)d_in[i]; break; // weight
            case OUT_DIM:                    pb = (const float*)d_in[i]; break; // bias
            case BB * N_SEQ:                 ps = (const int*)d_in[i];   break; // sourceIdx
            default: break;
        }
    }
    if (!px || !pw || !pb || !ps) {
        px = (const float*)d_in[0]; pw = (const float*)d_in[1];
        pb = (const float*)d_in[2]; ps = (const int*)d_in[3];
    }

    unsigned short* w2 = (unsigned short*)d_ws;      // 64 KB only
    float* out = (float*)d_out;

    k_wprep<<<16, 256, 0, stream>>>(pw, w2);
    k_gemm<<<dim3(N_REAL / 32, BB), 128, 0, stream>>>(px, w2, pb, ps, out);
}

// Round 10
// 72.030 us; speedup vs baseline: 2.8461x; 1.0125x over previous
//
#include <hip/hip_runtime.h>
#include <hip/hip_bf16.h>

#define BB 4
#define IN_DIM 8
#define OUT_DIM 64
#define N_WIN 64
#define N_SEQ 4096
#define N_REAL 6144
#define NTB (N_REAL / 32)   // 192 t-tiles per batch

typedef __attribute__((ext_vector_type(8)))  short short8;
typedef __attribute__((ext_vector_type(16))) float floatx16;

static __device__ __forceinline__ unsigned short f2bf(float f) {
    union { float f; unsigned int u; } v; v.f = f;
    unsigned int r = v.u + 0x7fffu + ((v.u >> 16) & 1u);   // round-nearest-even
    return (unsigned short)(r >> 16);
}

// ---- K1: pack weights w[o][i][l] -> w2[l][o][i] (bf16)  +  all 768 window
//          lower-bounds lob[b*NTB+bx] (parallel searches, hidden under transpose)
__global__ __launch_bounds__(256)
void k_prep(const float* __restrict__ w, const int* __restrict__ sidx,
            unsigned short* __restrict__ w2, int* __restrict__ lob)
{
    const int tg = blockIdx.x * 256 + threadIdx.x;   // 0..4095
    const int l = tg >> 6, o = tg & 63;              // consecutive tid -> consecutive o
    const float* wp = w + (size_t)o * (IN_DIM * N_WIN) + l;
    unsigned short v[8];
    #pragma unroll
    for (int i = 0; i < 8; ++i) v[i] = f2bf(wp[(size_t)i * N_WIN]);
    uint4 pk;
    pk.x = v[0] | ((unsigned)v[1] << 16); pk.y = v[2] | ((unsigned)v[3] << 16);
    pk.z = v[4] | ((unsigned)v[5] << 16); pk.w = v[6] | ((unsigned)v[7] << 16);
    *(uint4*)(w2 + ((size_t)(l * OUT_DIM + o)) * 8) = pk;    // coalesced 16B stores

    if (tg < BB * NTB) {                             // one thread per (b, t-tile)
        const int b  = tg / NTB, bx = tg - b * NTB;
        const int vlo = bx * 32 - 63;
        const int* idxb = sidx + b * N_SEQ;
        int lo = 0, hi = N_SEQ;
        while (lo < hi) { int m = (lo + hi) >> 1; if (idxb[m] < vlo) lo = m + 1; else hi = m; }
        lob[tg] = lo;
    }
}

// ---- K2: MFMA GEMM, 32 t x 64 o per block, 2 waves; latency-hidden prologue ----
__global__ __launch_bounds__(128)
void k_gemm(const float* __restrict__ x, const unsigned short* __restrict__ w2,
            const float* __restrict__ bias, const int* __restrict__ sidx,
            const int* __restrict__ lob, float* __restrict__ out)
{
    __shared__ unsigned short zlds[96 * 8];   // rows tau = t0-63 .. t0+32 (1.5 KB)

    const int tid = threadIdx.x;
    const int bx  = blockIdx.x;
    const int b   = blockIdx.y;
    const int t0  = bx * 32;
    const int vlo = t0 - 63;
    const int lo  = lob[b * NTB + bx];        // uniform -> scalar load

    // zero the LDS tile (384 dwords)
    unsigned int* zw = (unsigned int*)zlds;
    zw[tid] = 0u; zw[tid + 128] = 0u; zw[tid + 256] = 0u;

    // issue scatter-source loads NOW (coalesced; latency overlaps zero+barrier)
    const int ig = tid >> 4;                  // input channel 0..7
    const int sl = tid & 15;                  // source slot
    const int* idxb = sidx + b * N_SEQ;
    const float* xb = x + ((size_t)b * IN_DIM + ig) * N_SEQ;
    int   rarr[6]; float xv[6];
    #pragma unroll
    for (int c = 0; c < 6; ++c) {             // 6 x 16 slots cover <=96 sources
        int s = lo + c * 16 + sl;
        bool valid = (s < N_SEQ);
        rarr[c] = valid ? (idxb[s] - vlo) : -1;
        xv[c]   = valid ? xb[s] : 0.f;
    }

    // A-fragment prefetch (no LDS dependency)
    const int mh = tid >> 6;                  // wave: which 32-o half
    const int ln = tid & 31;                  // t / o lane coordinate
    const int lq = (tid >> 5) & 1;            // k-half within wave
    const short8* wv = (const short8*)w2;
    short8 apre[8];
    #pragma unroll
    for (int k = 0; k < 8; ++k)
        apre[k] = wv[(2 * k + lq) * OUT_DIM + mh * 32 + ln];

    __syncthreads();                          // zeros complete
    #pragma unroll
    for (int c = 0; c < 6; ++c)
        if ((unsigned)rarr[c] < 96u)
            zlds[rarr[c] * 8 + ig] = f2bf(xv[c]);
    __syncthreads();                          // scatter complete

    floatx16 acc = {};
    const short8* zv = (const short8*)zlds;
    #pragma unroll
    for (int ks = 0; ks < 32; ++ks) {
        const int l = 2 * ks + lq;                       // lag for this k-half
        short8 a  = (ks < 8) ? apre[ks]
                             : wv[l * OUT_DIM + mh * 32 + ln];   // L1/L2-hot
        short8 bz = zv[ln + 63 - l];                     // LDS b128
        acc = __builtin_amdgcn_mfma_f32_32x32x16_bf16(a, bz, acc, 0, 0, 0);
    }

    // C/D layout (m74/m101): col=lane&31 -> t, row=(p&3)+8*(p>>2)+4*(lane>>5) -> o
    #pragma unroll
    for (int p = 0; p < 16; ++p) {
        int o = (p & 3) + 8 * (p >> 2) + 4 * lq + mh * 32;
        out[((size_t)b * OUT_DIM + o) * N_REAL + t0 + ln] = acc[p] + bias[o];
    }
}

extern "C" void kernel_launch(void* const* d_in, const int* in_sizes, int n_in,
                              void* d_out, int out_size, void* d_ws, size_t ws_size,
                              hipStream_t stream) {
    const float* px = nullptr; const float* pw = nullptr;
    const float* pb = nullptr; const int* ps = nullptr;

    for (int i = 0; i < n_in; ++i) {
        switch (in_sizes[i]) {
            case BB * IN_DIM * N_SEQ:        px = (const float*)d_in[i]; break; // x
            case OUT_DIM * IN_DIM * N_WIN:   pw = (const float*)d_in[i]; break; // weight
            case OUT_DIM:                    pb = (const float*)d_in[i]; break; // bias
            case BB * N_SEQ:                 ps = (const int*)d_in[i];   break; // sourceIdx
            default: break;
        }
    }
    if (!px || !pw || !pb || !ps) {
        px = (const float*)d_in[0]; pw = (const float*)d_in[1];
        pb = (const float*)d_in[2]; ps = (const int*)d_in[3];
    }

    unsigned short* w2 = (unsigned short*)d_ws;                  // 64 KB
    int* lob = (int*)((char*)d_ws + 64 * 1024);                  // 3 KB
    float* out = (float*)d_out;

    k_prep<<<16, 256, 0, stream>>>(pw, ps, w2, lob);
    k_gemm<<<dim3(NTB, BB), 128, 0, stream>>>(px, w2, pb, ps, lob, out);
}